// Round 4
// baseline (778.559 us; speedup 1.0000x reference)
//
#include <hip/hip_runtime.h>
#include <math.h>

// GCN_homo: h = relu(D^-1/2 (A+I) D^-1/2 (x@Wg) + bg); MLP 16->16->32->1; sigmoid.
// N=100000, F=512, E=3200000. fp32; edge_index int32.
// R4: global atomics have a ~20 G op/s device budget (k_rank: 3.2M/150us).
// Replace rank+scan+scatter with bucket partition (128 nodes/bucket):
// per-block LDS histograms + bulk reservation => only ~400K global atomics
// total; gather accumulates in LDS (ds_add_f32) instead of reading CSR rows.

static constexpr int F = 512;
static constexpr int C = 16;
static constexpr int BSH = 7;              // bucket shift: 128 nodes per bucket
static constexpr int BSZ = 128;            // nodes per bucket
static constexpr int NBMAX = 1024;         // max buckets (n <= 131072)
static constexpr int EPB = 16384;          // edges per partition block (256 thr x 64)

// K1: xw[row] = x[row] @ Wg  (also zeroes bcnt[0..1024)).
__global__ __launch_bounds__(256) void k_xw(const float* __restrict__ x,
                                            const float* __restrict__ Wg,
                                            float* __restrict__ xw,
                                            int* __restrict__ bcnt, int n)
{
    int row = blockIdx.x * 256 + threadIdx.x;
    if (row < NBMAX) bcnt[row] = 0;
    if (row >= n) return;
    float acc[C];
#pragma unroll
    for (int c = 0; c < C; ++c) acc[c] = 0.f;
    const float4* xr = (const float4*)(x + (size_t)row * F);
#pragma unroll 4
    for (int k4 = 0; k4 < F / 4; ++k4) {
        float4 xv = xr[k4];
        const float* w = Wg + k4 * 4 * C;  // uniform -> s_load
#pragma unroll
        for (int j = 0; j < 4; ++j) {
            float xs = (j == 0) ? xv.x : (j == 1) ? xv.y : (j == 2) ? xv.z : xv.w;
#pragma unroll
            for (int c = 0; c < C; ++c)
                acc[c] = fmaf(xs, w[j * C + c], acc[c]);
        }
    }
    float4* o = (float4*)(xw + (size_t)row * C);
#pragma unroll
    for (int q = 0; q < 4; ++q)
        o[q] = make_float4(acc[4 * q + 0], acc[4 * q + 1], acc[4 * q + 2], acc[4 * q + 3]);
}

// Bucket histogram: LDS hist per 16K-edge block, 1024 global atomics per block.
__global__ __launch_bounds__(256) void k_bcount(const int* __restrict__ dst,
                                                int* __restrict__ bcnt, int E)
{
    __shared__ int hist[NBMAX];
    for (int i = threadIdx.x; i < NBMAX; i += 256) hist[i] = 0;
    __syncthreads();
    int base = blockIdx.x * EPB;
#pragma unroll 4
    for (int j = 0; j < EPB / 256; ++j) {
        int e = base + j * 256 + threadIdx.x;
        if (e < E) atomicAdd(&hist[dst[e] >> BSH], 1);
    }
    __syncthreads();
    for (int i = threadIdx.x; i < NBMAX; i += 256) {
        int v = hist[i];
        if (v) atomicAdd(&bcnt[i], v);
    }
}

// Exclusive scan of 1024 bucket counts -> bstart and working cursor gcur.
__global__ __launch_bounds__(1024) void k_bscan(const int* __restrict__ bcnt,
                                                int* __restrict__ bstart,
                                                int* __restrict__ gcur)
{
    __shared__ int sh[NBMAX];
    int t = threadIdx.x;
    int v = bcnt[t];
    sh[t] = v;
    __syncthreads();
    for (int d = 1; d < NBMAX; d <<= 1) {
        int u = (t >= d) ? sh[t - d] : 0;
        __syncthreads();
        sh[t] += u;
        __syncthreads();
    }
    int ex = sh[t] - v;
    bstart[t] = ex;
    gcur[t] = ex;
    if (t == NBMAX - 1) bstart[NBMAX] = sh[t];
}

// Partition edges into buckets: LDS hist -> bulk reserve -> scatter packed
// (src | dst_local<<17). Order within bucket is arbitrary (sum commutes).
__global__ __launch_bounds__(256) void k_bscatter(const int* __restrict__ ei,
                                                  int* __restrict__ gcur,
                                                  int* __restrict__ packed, int E)
{
    __shared__ int hist[NBMAX];
    __shared__ int sbase[NBMAX];
    for (int i = threadIdx.x; i < NBMAX; i += 256) hist[i] = 0;
    __syncthreads();
    int base = blockIdx.x * EPB;
    // phase A: local count
#pragma unroll 4
    for (int j = 0; j < EPB / 256; ++j) {
        int e = base + j * 256 + threadIdx.x;
        if (e < E) atomicAdd(&hist[ei[E + e] >> BSH], 1);
    }
    __syncthreads();
    // phase B: reserve global ranges, reset local cursors
    for (int i = threadIdx.x; i < NBMAX; i += 256) {
        int v = hist[i];
        sbase[i] = v ? atomicAdd(&gcur[i], v) : 0;
        hist[i] = 0;
    }
    __syncthreads();
    // phase C: scatter
#pragma unroll 2
    for (int j = 0; j < EPB / 256; ++j) {
        int e = base + j * 256 + threadIdx.x;
        if (e < E) {
            int d = ei[E + e];
            int s = ei[e];
            int b = d >> BSH;
            int r = atomicAdd(&hist[b], 1);
            packed[sbase[b] + r] = s | ((d & (BSZ - 1)) << 17);
        }
    }
}

// Per-bucket: degree from LDS hist of packed edges -> dinv; scale y rows in place.
__global__ __launch_bounds__(256) void k_bdeg_scale(const int* __restrict__ packed,
                                                    const int* __restrict__ bstart,
                                                    float* __restrict__ y,
                                                    float* __restrict__ dinv, int n)
{
    int b = blockIdx.x;
    __shared__ int hist[BSZ];
    __shared__ float sdi[BSZ];
    if (threadIdx.x < BSZ) hist[threadIdx.x] = 0;
    __syncthreads();
    int beg = bstart[b], end = bstart[b + 1];
    for (int e = beg + threadIdx.x; e < end; e += 256)
        atomicAdd(&hist[(packed[e] >> 17) & (BSZ - 1)], 1);
    __syncthreads();
    int node0 = b << BSH;
    if (threadIdx.x < BSZ) {
        int node = node0 + threadIdx.x;
        float di = (node < n) ? rsqrtf((float)(hist[threadIdx.x] + 1)) : 0.f;
        sdi[threadIdx.x] = di;
        if (node < n) dinv[node] = di;
    }
    __syncthreads();
    int nnode = n - node0; if (nnode > BSZ) nnode = BSZ;
    int lim = nnode * 4;  // float4s
    float4* yv = (float4*)(y + (size_t)node0 * C);
    for (int i = threadIdx.x; i < lim; i += 256) {
        float di = sdi[i >> 2];
        float4 v = yv[i];
        v.x *= di; v.y *= di; v.z *= di; v.w *= di;
        yv[i] = v;
    }
}

// Per-bucket gather: LDS accumulator acc[128][17] (odd stride -> uniform banks),
// ds_add_f32 per channel; epilogue fuses self-loop + dinv + bias + relu.
__global__ __launch_bounds__(256) void k_bgather(const float* __restrict__ y,
                                                 const int* __restrict__ packed,
                                                 const int* __restrict__ bstart,
                                                 const float* __restrict__ dinv,
                                                 const float* __restrict__ bg,
                                                 float* __restrict__ h, int n)
{
    int b = blockIdx.x;
    __shared__ float acc[BSZ][17];
    for (int i = threadIdx.x; i < BSZ * 17; i += 256) ((float*)acc)[i] = 0.f;
    __syncthreads();
    int beg = bstart[b], end = bstart[b + 1];
    for (int e = beg + threadIdx.x; e < end; e += 256) {
        int p = packed[e];
        int s = p & 0x1FFFF;
        int dl = (p >> 17) & (BSZ - 1);
        const float4* yr = (const float4*)(y + (size_t)s * C);
        float4 v0 = yr[0], v1 = yr[1], v2 = yr[2], v3 = yr[3];
        float* a = acc[dl];
        atomicAdd(a + 0,  v0.x); atomicAdd(a + 1,  v0.y);
        atomicAdd(a + 2,  v0.z); atomicAdd(a + 3,  v0.w);
        atomicAdd(a + 4,  v1.x); atomicAdd(a + 5,  v1.y);
        atomicAdd(a + 6,  v1.z); atomicAdd(a + 7,  v1.w);
        atomicAdd(a + 8,  v2.x); atomicAdd(a + 9,  v2.y);
        atomicAdd(a + 10, v2.z); atomicAdd(a + 11, v2.w);
        atomicAdd(a + 12, v3.x); atomicAdd(a + 13, v3.y);
        atomicAdd(a + 14, v3.z); atomicAdd(a + 15, v3.w);
    }
    __syncthreads();
    int node0 = b << BSH;
    for (int i = threadIdx.x; i < BSZ * 4; i += 256) {  // 128 nodes x 4 quads
        int dl = i >> 2, q = i & 3;
        int node = node0 + dl;
        if (node >= n) continue;
        float di = dinv[node];
        float4 v = ((const float4*)(y + (size_t)node * C))[q];  // self-loop (scaled)
        const float* a = acc[dl] + 4 * q;
        const float* bq = bg + 4 * q;
        float4 r;
        r.x = fmaxf(fmaf(a[0] + v.x, di, bq[0]), 0.f);
        r.y = fmaxf(fmaf(a[1] + v.y, di, bq[1]), 0.f);
        r.z = fmaxf(fmaf(a[2] + v.z, di, bq[2]), 0.f);
        r.w = fmaxf(fmaf(a[3] + v.w, di, bq[3]), 0.f);
        ((float4*)(h + (size_t)node * C))[q] = r;
    }
}

// MLP: h1 = relu(h@W1+b1); h2 = relu(h1@W2+b2); out = sigmoid(h2@W3+b3)
__global__ __launch_bounds__(256) void k_mlp(const float* __restrict__ hbuf,
                                             const float* __restrict__ W1,
                                             const float* __restrict__ b1,
                                             const float* __restrict__ W2,
                                             const float* __restrict__ b2,
                                             const float* __restrict__ W3,
                                             const float* __restrict__ b3,
                                             float* __restrict__ out, int n)
{
    int i = blockIdx.x * 256 + threadIdx.x;
    if (i >= n) return;
    float h[16];
    const float4* hr = (const float4*)(hbuf + (size_t)i * C);
#pragma unroll
    for (int q = 0; q < 4; ++q) {
        float4 v = hr[q];
        h[4 * q + 0] = v.x; h[4 * q + 1] = v.y; h[4 * q + 2] = v.z; h[4 * q + 3] = v.w;
    }
    float h1[16];
#pragma unroll
    for (int c = 0; c < 16; ++c) {
        float s = b1[c];
#pragma unroll
        for (int k = 0; k < 16; ++k) s = fmaf(h[k], W1[k * 16 + c], s);
        h1[c] = fmaxf(s, 0.f);
    }
    float h2[32];
#pragma unroll
    for (int c = 0; c < 32; ++c) {
        float s = b2[c];
#pragma unroll
        for (int k = 0; k < 16; ++k) s = fmaf(h1[k], W2[k * 32 + c], s);
        h2[c] = fmaxf(s, 0.f);
    }
    float s = b3[0];
#pragma unroll
    for (int k = 0; k < 32; ++k) s = fmaf(h2[k], W3[k], s);
    out[i] = 1.f / (1.f + expf(-s));
}

extern "C" void kernel_launch(void* const* d_in, const int* in_sizes, int n_in,
                              void* d_out, int out_size, void* d_ws, size_t ws_size,
                              hipStream_t stream)
{
    const float* x  = (const float*)d_in[0];
    const int*   ei = (const int*)d_in[1];   // [2,E]: src at [e], dst at [E+e]
    const float* Wg = (const float*)d_in[2];
    const float* bg = (const float*)d_in[3];
    const float* W1 = (const float*)d_in[4];
    const float* b1 = (const float*)d_in[5];
    const float* W2 = (const float*)d_in[6];
    const float* b2 = (const float*)d_in[7];
    const float* W3 = (const float*)d_in[8];
    const float* b3 = (const float*)d_in[9];
    float* out = (float*)d_out;

    int n = in_sizes[0] / F;   // 100000
    int E = in_sizes[1] / 2;   // 3200000

    // ws: y[n*16] | h[n*16] | packed[E] | bcnt[1024] | bstart[1025->1028] | gcur[1024] | dinv[n]
    char* ws = (char*)d_ws;
    size_t off = 0;
    float* y      = (float*)(ws + off); off += (size_t)n * C * sizeof(float);
    float* h      = (float*)(ws + off); off += (size_t)n * C * sizeof(float);
    int*   packed = (int*)  (ws + off); off += (size_t)E * sizeof(int);
    int*   bcnt   = (int*)  (ws + off); off += NBMAX * sizeof(int);
    int*   bstart = (int*)  (ws + off); off += (NBMAX + 4) * sizeof(int);
    int*   gcur   = (int*)  (ws + off); off += NBMAX * sizeof(int);
    float* dinv   = (float*)(ws + off);

    int gb  = (n + 255) / 256;
    int geb = (E + EPB - 1) / EPB;          // 196
    int NB  = (n + BSZ - 1) >> BSH;         // 782

    k_xw<<<gb, 256, 0, stream>>>(x, Wg, y, bcnt, n);
    k_bcount<<<geb, 256, 0, stream>>>(ei + E, bcnt, E);
    k_bscan<<<1, 1024, 0, stream>>>(bcnt, bstart, gcur);
    k_bscatter<<<geb, 256, 0, stream>>>(ei, gcur, packed, E);
    k_bdeg_scale<<<NB, 256, 0, stream>>>(packed, bstart, y, dinv, n);
    k_bgather<<<NB, 256, 0, stream>>>(y, packed, bstart, dinv, bg, h, n);
    k_mlp<<<gb, 256, 0, stream>>>(h, W1, b1, W2, b2, W3, b3, out, n);
}

// Round 5
// 509.429 us; speedup vs baseline: 1.5283x; 1.5283x over previous
//
#include <hip/hip_runtime.h>
#include <math.h>

// GCN_homo: h = relu(D^-1/2 (A+I) D^-1/2 (x@Wg) + bg); MLP 16->16->32->1; sigmoid.
// N=100000, F=512, E=3200000. fp32; edge_index int32.
// R5: zero global atomics. Bucket partition via per-block histograms +
// column scan (replaces k_rank's 150us @ ~20G atomics/s budget), per-bucket
// CSR build in LDS, then R3's register-accumulating gather (k_bgather's LDS
// ds_add approach regressed: 338us, 19% occupancy).

static constexpr int F = 512;
static constexpr int C = 16;
static constexpr int BSH = 7;       // 128 nodes per bucket
static constexpr int BSZ = 128;
static constexpr int NBMAX = 1024;  // max buckets (n <= 131072)
static constexpr int EPB = 16384;   // edges per partition block

// K1: xw[row] = x[row] @ Wg.
__global__ __launch_bounds__(256) void k_xw(const float* __restrict__ x,
                                            const float* __restrict__ Wg,
                                            float* __restrict__ xw, int n)
{
    int row = blockIdx.x * 256 + threadIdx.x;
    if (row >= n) return;
    float acc[C];
#pragma unroll
    for (int c = 0; c < C; ++c) acc[c] = 0.f;
    const float4* xr = (const float4*)(x + (size_t)row * F);
#pragma unroll 4
    for (int k4 = 0; k4 < F / 4; ++k4) {
        float4 xv = xr[k4];
        const float* w = Wg + k4 * 4 * C;  // uniform -> s_load
#pragma unroll
        for (int j = 0; j < 4; ++j) {
            float xs = (j == 0) ? xv.x : (j == 1) ? xv.y : (j == 2) ? xv.z : xv.w;
#pragma unroll
            for (int c = 0; c < C; ++c)
                acc[c] = fmaf(xs, w[j * C + c], acc[c]);
        }
    }
    float4* o = (float4*)(xw + (size_t)row * C);
#pragma unroll
    for (int q = 0; q < 4; ++q)
        o[q] = make_float4(acc[4 * q + 0], acc[4 * q + 1], acc[4 * q + 2], acc[4 * q + 3]);
}

// Per-block bucket histogram -> bh[block][0..1024). No global atomics.
__global__ __launch_bounds__(256) void k_bcount(const int* __restrict__ dst,
                                                int* __restrict__ bh, int E)
{
    __shared__ int hist[NBMAX];
    for (int i = threadIdx.x; i < NBMAX; i += 256) hist[i] = 0;
    __syncthreads();
    int base = blockIdx.x * EPB;
#pragma unroll 4
    for (int j = 0; j < EPB / 256; ++j) {
        int e = base + j * 256 + threadIdx.x;
        if (e < E) atomicAdd(&hist[dst[e] >> BSH], 1);
    }
    __syncthreads();
    int* row = bh + (size_t)blockIdx.x * NBMAX;
    for (int i = threadIdx.x; i < NBMAX; i += 256) row[i] = hist[i];
}

// Column-wise exclusive scan over blocks: bh[g][b] -> prefix; total[b] = sum.
__global__ __launch_bounds__(256) void k_colscan(int* __restrict__ bh,
                                                 int* __restrict__ total, int geb)
{
    int b = blockIdx.x * 256 + threadIdx.x;  // grid = 4 x 256 = NBMAX
    int run = 0;
#pragma unroll 4
    for (int g = 0; g < geb; ++g) {
        size_t idx = (size_t)g * NBMAX + b;
        int v = bh[idx];
        bh[idx] = run;
        run += v;
    }
    total[b] = run;
}

// Exclusive scan of bucket totals -> bstart[0..NBMAX].
__global__ __launch_bounds__(1024) void k_bscan(const int* __restrict__ total,
                                                int* __restrict__ bstart)
{
    __shared__ int sh[NBMAX];
    int t = threadIdx.x;
    int v = total[t];
    sh[t] = v;
    __syncthreads();
    for (int d = 1; d < NBMAX; d <<= 1) {
        int u = (t >= d) ? sh[t - d] : 0;
        __syncthreads();
        sh[t] += u;
        __syncthreads();
    }
    bstart[t] = sh[t] - v;
    if (t == NBMAX - 1) bstart[NBMAX] = sh[t];
}

// Partition: absolute cursors from bstart + own prefix row; LDS atomics only.
__global__ __launch_bounds__(256) void k_bscatter(const int* __restrict__ ei,
                                                  const int* __restrict__ bh,
                                                  const int* __restrict__ bstart,
                                                  int* __restrict__ packed, int E)
{
    __shared__ int cur[NBMAX];
    int g = blockIdx.x;
    const int* row = bh + (size_t)g * NBMAX;
    for (int i = threadIdx.x; i < NBMAX; i += 256) cur[i] = bstart[i] + row[i];
    __syncthreads();
    int base = g * EPB;
#pragma unroll 2
    for (int j = 0; j < EPB / 256; ++j) {
        int e = base + j * 256 + threadIdx.x;
        if (e < E) {
            int d = ei[E + e];
            int s = ei[e];
            int b = d >> BSH;
            int r = atomicAdd(&cur[b], 1);
            packed[r] = s | ((d & (BSZ - 1)) << 17);
        }
    }
}

// Per-bucket CSR build: LDS hist -> local scan -> srcs/starts/cnt/dinv;
// scales this bucket's y rows in place.
__global__ __launch_bounds__(256) void k_bcsr(const int* __restrict__ packed,
                                              const int* __restrict__ bstart,
                                              float* __restrict__ y,
                                              int* __restrict__ srcs,
                                              int* __restrict__ starts,
                                              int* __restrict__ cnt,
                                              float* __restrict__ dinv, int n)
{
    int b = blockIdx.x, t = threadIdx.x;
    __shared__ int hist[BSZ];
    __shared__ int sc[BSZ];
    __shared__ float sdi[BSZ];
    if (t < BSZ) hist[t] = 0;
    __syncthreads();
    int beg = bstart[b], end = bstart[b + 1];
    for (int e = beg + t; e < end; e += 256)
        atomicAdd(&hist[(packed[e] >> 17) & (BSZ - 1)], 1);
    __syncthreads();
    int myc = 0;
    if (t < BSZ) { myc = hist[t]; sc[t] = myc; }
    __syncthreads();
    for (int d = 1; d < BSZ; d <<= 1) {
        int u = 0;
        if (t < BSZ && t >= d) u = sc[t - d];
        __syncthreads();
        if (t < BSZ) sc[t] += u;
        __syncthreads();
    }
    int node0 = b << BSH;
    if (t < BSZ) {
        int lst = sc[t] - myc;   // exclusive local offset
        sc[t] = lst;
        float di = rsqrtf((float)(myc + 1));
        sdi[t] = di;
        int node = node0 + t;
        if (node < n) { starts[node] = beg + lst; cnt[node] = myc; dinv[node] = di; }
        hist[t] = 0;             // reuse as cursor
    }
    __syncthreads();
    for (int e = beg + t; e < end; e += 256) {
        int p = packed[e];
        int dl = (p >> 17) & (BSZ - 1);
        int r = atomicAdd(&hist[dl], 1);
        srcs[beg + sc[dl] + r] = p & 0x1FFFF;
    }
    // scale this bucket's y rows by dinv
    int nn = n - node0; if (nn > BSZ) nn = BSZ;
    if (nn <= 0) return;
    int lim = nn * 4;
    float4* yv = (float4*)(y + (size_t)node0 * C);
    for (int i = t; i < lim; i += 256) {
        float di = sdi[i >> 2];
        float4 v = yv[i];
        v.x *= di; v.y *= di; v.z *= di; v.w *= di;
        yv[i] = v;
    }
}

// Gather (R3): 4 threads/node, register acc, int4 srcs loads, fused epilogue.
__global__ __launch_bounds__(256) void k_gather(const float* __restrict__ y,
                                                const int* __restrict__ srcs,
                                                const int* __restrict__ starts,
                                                const int* __restrict__ cnt,
                                                const float* __restrict__ dinv,
                                                const float* __restrict__ bg,
                                                float* __restrict__ h, int n)
{
    int tid = blockIdx.x * 256 + threadIdx.x;
    int i = tid >> 2;
    if (i >= n) return;
    int q = tid & 3;
    const float4* yv = (const float4*)y;
    float4 acc = yv[(size_t)i * 4 + q];  // self-loop term (y pre-scaled)
    int beg = starts[i];
    int end = beg + cnt[i];
    int e = beg;
    int headEnd = (beg + 3) & ~3;
    if (headEnd > end) headEnd = end;
    for (; e < headEnd; ++e) {
        float4 v = yv[(size_t)srcs[e] * 4 + q];
        acc.x += v.x; acc.y += v.y; acc.z += v.z; acc.w += v.w;
    }
    for (; e + 4 <= end; e += 4) {
        int4 s4 = *(const int4*)(srcs + e);
        float4 v0 = yv[(size_t)s4.x * 4 + q];
        float4 v1 = yv[(size_t)s4.y * 4 + q];
        float4 v2 = yv[(size_t)s4.z * 4 + q];
        float4 v3 = yv[(size_t)s4.w * 4 + q];
        acc.x += v0.x + v1.x + v2.x + v3.x;
        acc.y += v0.y + v1.y + v2.y + v3.y;
        acc.z += v0.z + v1.z + v2.z + v3.z;
        acc.w += v0.w + v1.w + v2.w + v3.w;
    }
    for (; e < end; ++e) {
        float4 v = yv[(size_t)srcs[e] * 4 + q];
        acc.x += v.x; acc.y += v.y; acc.z += v.z; acc.w += v.w;
    }
    float di = dinv[i];
    const float* bq = bg + q * 4;
    float4 r;
    r.x = fmaxf(fmaf(acc.x, di, bq[0]), 0.f);
    r.y = fmaxf(fmaf(acc.y, di, bq[1]), 0.f);
    r.z = fmaxf(fmaf(acc.z, di, bq[2]), 0.f);
    r.w = fmaxf(fmaf(acc.w, di, bq[3]), 0.f);
    ((float4*)(h + (size_t)i * C))[q] = r;
}

// MLP: h1 = relu(h@W1+b1); h2 = relu(h1@W2+b2); out = sigmoid(h2@W3+b3)
__global__ __launch_bounds__(256) void k_mlp(const float* __restrict__ hbuf,
                                             const float* __restrict__ W1,
                                             const float* __restrict__ b1,
                                             const float* __restrict__ W2,
                                             const float* __restrict__ b2,
                                             const float* __restrict__ W3,
                                             const float* __restrict__ b3,
                                             float* __restrict__ out, int n)
{
    int i = blockIdx.x * 256 + threadIdx.x;
    if (i >= n) return;
    float h[16];
    const float4* hr = (const float4*)(hbuf + (size_t)i * C);
#pragma unroll
    for (int q = 0; q < 4; ++q) {
        float4 v = hr[q];
        h[4 * q + 0] = v.x; h[4 * q + 1] = v.y; h[4 * q + 2] = v.z; h[4 * q + 3] = v.w;
    }
    float h1[16];
#pragma unroll
    for (int c = 0; c < 16; ++c) {
        float s = b1[c];
#pragma unroll
        for (int k = 0; k < 16; ++k) s = fmaf(h[k], W1[k * 16 + c], s);
        h1[c] = fmaxf(s, 0.f);
    }
    float h2[32];
#pragma unroll
    for (int c = 0; c < 32; ++c) {
        float s = b2[c];
#pragma unroll
        for (int k = 0; k < 16; ++k) s = fmaf(h1[k], W2[k * 32 + c], s);
        h2[c] = fmaxf(s, 0.f);
    }
    float s = b3[0];
#pragma unroll
    for (int k = 0; k < 32; ++k) s = fmaf(h2[k], W3[k], s);
    out[i] = 1.f / (1.f + expf(-s));
}

extern "C" void kernel_launch(void* const* d_in, const int* in_sizes, int n_in,
                              void* d_out, int out_size, void* d_ws, size_t ws_size,
                              hipStream_t stream)
{
    const float* x  = (const float*)d_in[0];
    const int*   ei = (const int*)d_in[1];   // [2,E]: src at [e], dst at [E+e]
    const float* Wg = (const float*)d_in[2];
    const float* bg = (const float*)d_in[3];
    const float* W1 = (const float*)d_in[4];
    const float* b1 = (const float*)d_in[5];
    const float* W2 = (const float*)d_in[6];
    const float* b2 = (const float*)d_in[7];
    const float* W3 = (const float*)d_in[8];
    const float* b3 = (const float*)d_in[9];
    float* out = (float*)d_out;

    int n = in_sizes[0] / F;   // 100000
    int E = in_sizes[1] / 2;   // 3200000

    int gb  = (n + 255) / 256;
    int geb = (E + EPB - 1) / EPB;          // 196
    int NB  = (n + BSZ - 1) >> BSH;         // 782

    // ws: y[n*16] | h[n*16] | packed[E] | srcs[E] (aliases bh[geb*1024]; disjoint
    //     lifetimes: bh used bcount..bscatter, srcs used bcsr..gather) |
    //     starts[n] | cnt[n] | dinv[n] | total[1024] | bstart[1025]
    char* ws = (char*)d_ws;
    size_t off = 0;
    float* y      = (float*)(ws + off); off += (size_t)n * C * sizeof(float);
    float* h      = (float*)(ws + off); off += (size_t)n * C * sizeof(float);
    int*   packed = (int*)  (ws + off); off += (size_t)E * sizeof(int);
    int*   srcs   = (int*)  (ws + off);
    int*   bh     = srcs;  // alias, disjoint lifetime
    size_t big = (size_t)E; if ((size_t)geb * NBMAX > big) big = (size_t)geb * NBMAX;
    off += big * sizeof(int);
    int*   starts = (int*)  (ws + off); off += (size_t)((n + 3) & ~3) * sizeof(int);
    int*   cnt    = (int*)  (ws + off); off += (size_t)((n + 3) & ~3) * sizeof(int);
    float* dinv   = (float*)(ws + off); off += (size_t)((n + 3) & ~3) * sizeof(float);
    int*   total  = (int*)  (ws + off); off += NBMAX * sizeof(int);
    int*   bstart = (int*)  (ws + off);

    k_xw<<<gb, 256, 0, stream>>>(x, Wg, y, n);
    k_bcount<<<geb, 256, 0, stream>>>(ei + E, bh, E);
    k_colscan<<<NBMAX / 256, 256, 0, stream>>>(bh, total, geb);
    k_bscan<<<1, 1024, 0, stream>>>(total, bstart);
    k_bscatter<<<geb, 256, 0, stream>>>(ei, bh, bstart, packed, E);
    k_bcsr<<<NB, 256, 0, stream>>>(packed, bstart, y, srcs, starts, cnt, dinv, n);
    k_gather<<<(n * 4 + 255) / 256, 256, 0, stream>>>(y, srcs, starts, cnt, dinv, bg, h, n);
    k_mlp<<<gb, 256, 0, stream>>>(h, W1, b1, W2, b2, W3, b3, out, n);
}